// Round 11
// baseline (1268.613 us; speedup 1.0000x reference)
//
#include <hip/hip_runtime.h>

typedef unsigned short u16;
typedef unsigned int u32;
typedef __bf16 bf16x8 __attribute__((ext_vector_type(8)));
typedef float f32x4 __attribute__((ext_vector_type(4)));
typedef float f32x2 __attribute__((ext_vector_type(2)));

#define AS_STRIDE 136   // bf16 elems per LDS A-row (128 + 8 pad; 16B-aligned rows)

__device__ __forceinline__ u16 f2bf1(float f) {
  union { __bf16 h; u16 u; } c; c.h = (__bf16)f; return c.u;
}
__device__ __forceinline__ u32 cvt2bf(float a, float b) {
  union { __bf16 h[2]; u32 u; } c; c.h[0] = (__bf16)a; c.h[1] = (__bf16)b; return c.u;
}
__device__ __forceinline__ float bf2f(u16 u) {
  union { u32 u; float f; } v; v.u = ((u32)u) << 16; return v.f;
}
// silu via v_rcp_f32 (2 ops) instead of IEEE f32 divide (~10-op sequence)
__device__ __forceinline__ float silu_f(float a) {
  return a * __builtin_amdgcn_rcpf(1.f + __expf(-a));
}
__device__ __forceinline__ float rsq_f(float x) {
  return __builtin_amdgcn_rsqf(x);
}
__device__ __forceinline__ f32x2 unpk2(u32 p) {
  union { u32 u; float f; } a, b;
  a.u = p << 16; b.u = p & 0xffff0000u;
  return (f32x2){a.f, b.f};
}

// ---------------- edge sort by dst (counting sort, once per call) ------------
__global__ void edge_hist(const int* __restrict__ edst, int E, int* __restrict__ cnt) {
  int i = blockIdx.x * blockDim.x + threadIdx.x;
  if (i < E) atomicAdd(&cnt[edst[i]], 1);
}

__global__ __launch_bounds__(1024)
void scan_kernel(const int* __restrict__ cnt, int* __restrict__ cursor, int Nn) {
  __shared__ int part[1024];
  int t = threadIdx.x;
  int per = (Nn + 1023) / 1024;
  int b = t * per;
  int s = 0;
  for (int i = 0; i < per; i++) { int idx = b + i; if (idx < Nn) s += cnt[idx]; }
  part[t] = s;
  __syncthreads();
  for (int d = 1; d < 1024; d <<= 1) {
    int v = (t >= d) ? part[t - d] : 0;
    __syncthreads();
    part[t] += v;
    __syncthreads();
  }
  int excl = (t == 0) ? 0 : part[t - 1];
  for (int i = 0; i < per; i++) {
    int idx = b + i;
    if (idx < Nn) { cursor[idx] = excl; excl += cnt[idx]; }
  }
}

__global__ void edge_scatter(const int* __restrict__ esrc, const int* __restrict__ edst,
                             int E, int* __restrict__ cursor,
                             int* __restrict__ ssrc, int* __restrict__ sdst) {
  int i = blockIdx.x * blockDim.x + threadIdx.x;
  if (i < E) {
    int d = edst[i];
    int p = atomicAdd(&cursor[d], 1);
    ssrc[p] = esrc[i];
    sdst[p] = d;
  }
}

// ---------------- weight prep: transpose + bf16-cast -------------------------
__global__ void prep_weights(const float* __restrict__ e_w1, const float* __restrict__ e_w2,
                             const float* __restrict__ n_w1, const float* __restrict__ n_w2,
                             u16* __restrict__ eW1T, u16* __restrict__ eW2T,
                             u16* __restrict__ nW1T, u16* __restrict__ nW2T) {
  int i = blockIdx.x * blockDim.x + threadIdx.x;
  const int s1 = 3 * 128 * 256;
  const int s2 = 3 * 128 * 128;
  if (i < s1) {
    int l = i / 32768, r = i % 32768, n = r >> 8, k = r & 255;
    eW1T[i] = f2bf1(e_w1[l * 33408 + k * 128 + n]);
  } else if (i < s1 + s2) {
    int j = i - s1; int l = j / 16384, r = j % 16384, n = r >> 7, k = r & 127;
    eW2T[j] = f2bf1(e_w2[l * 16384 + k * 128 + n]);
  } else if (i < s1 + s2 + s1) {
    int j = i - s1 - s2; int l = j / 32768, r = j % 32768, n = r >> 8, k = r & 255;
    nW1T[j] = f2bf1(n_w1[l * 32768 + k * 128 + n]);
  } else if (i < 2 * s1 + 2 * s2) {
    int j = i - 2 * s1 - s2; int l = j / 16384, r = j % 16384, n = r >> 7, k = r & 127;
    nW2T[j] = f2bf1(n_w2[l * 16384 + k * 128 + n]);
  }
}

// enc/dec weights + edge-attr weight
__global__ void prep_weights2(const float* __restrict__ enc_w1, const float* __restrict__ enc_w2,
                              const float* __restrict__ dec_w1, const float* __restrict__ dec_w2,
                              const float* __restrict__ dec_w3, const float* __restrict__ e_w1,
                              u16* __restrict__ encW1T, u16* __restrict__ encW2T,
                              u16* __restrict__ decW1T, u16* __restrict__ decW2T,
                              u16* __restrict__ decW3T, u16* __restrict__ eW1cT) {
  int i = blockIdx.x * blockDim.x + threadIdx.x;
  if (i < 4096) {
    int n = i >> 5, k = i & 31;
    encW1T[i] = (k < 7) ? f2bf1(enc_w1[k * 128 + n]) : (u16)0;
  } else if (i < 20480) {
    int j = i - 4096; int n = j >> 7, k = j & 127;
    encW2T[j] = f2bf1(enc_w2[k * 128 + n]);
  } else if (i < 36864) {
    int j = i - 20480; int n = j >> 7, k = j & 127;
    decW1T[j] = f2bf1(dec_w1[k * 128 + n]);
  } else if (i < 45056) {
    int j = i - 36864; int n = j >> 7, k = j & 127;
    decW2T[j] = f2bf1(dec_w2[k * 64 + n]);
  } else if (i < 46080) {
    int j = i - 45056; int n = j >> 6, k = j & 63;
    decW3T[j] = (n < 6) ? f2bf1(dec_w3[k * 6 + n]) : (u16)0;
  } else if (i < 58368) {
    int j = i - 46080; int l = j / 4096, r = j % 4096, n = r >> 5, k = r & 31;
    eW1cT[j] = (k < 5) ? f2bf1(e_w1[l * 33408 + (256 + k) * 128 + n]) : (u16)0;
  }
}

// ------- encoder (MFMA, 32-row tiles) + fused hd/hs for layer 0 --------------
__global__ __launch_bounds__(256, 6)
void encoder_mfma(const float* __restrict__ x,
                  const u16* __restrict__ W1T,   // [128][32]
                  const float* __restrict__ b1,
                  const float* __restrict__ g, const float* __restrict__ be,
                  const u16* __restrict__ W2T,   // [128][128]
                  const float* __restrict__ b2,
                  const u16* __restrict__ eW1T0, // [128][256] layer-0 edge W1
                  const float* __restrict__ eb10,
                  u16* __restrict__ hbf, u16* __restrict__ hd_all,
                  u16* __restrict__ hs_all, int Nn) {
  __shared__ __align__(16) u16 As[32 * 40];
  __shared__ __align__(16) u16 ts[32 * AS_STRIDE];
  const int tid = threadIdx.x;
  const int m0 = blockIdx.x * 32;
  const int w = tid >> 6, lane = tid & 63, quad = lane >> 4, l16 = lane & 15;
  const int c0w = w * 32;

  if (tid < 32) {
    int node = m0 + tid; if (node >= Nn) node = Nn - 1;
    union { u16 us[32]; uint4 v[4]; } pk;
    #pragma unroll
    for (int k = 0; k < 32; k++) pk.us[k] = 0;
    #pragma unroll
    for (int k = 0; k < 7; k++) pk.us[k] = f2bf1(x[node * 7 + k]);
    #pragma unroll
    for (int k = 0; k < 4; k++) *(uint4*)(As + tid * 40 + k * 8) = pk.v[k];
  }
  __syncthreads();

  f32x4 acc[2][2];
  #pragma unroll
  for (int rt = 0; rt < 2; rt++)
    #pragma unroll
    for (int ct = 0; ct < 2; ct++)
      acc[rt][ct] = (f32x4){0.f, 0.f, 0.f, 0.f};
  {
    const int kl = quad * 8;
    bf16x8 af[2];
    #pragma unroll
    for (int rt = 0; rt < 2; rt++)
      af[rt] = *(const bf16x8*)(As + (rt * 16 + l16) * 40 + kl);
    #pragma unroll
    for (int ct = 0; ct < 2; ct++) {
      bf16x8 bfv = *(const bf16x8*)(W1T + (c0w + ct * 16 + l16) * 32 + kl);
      #pragma unroll
      for (int rt = 0; rt < 2; rt++)
        acc[rt][ct] = __builtin_amdgcn_mfma_f32_16x16x32_bf16(af[rt], bfv, acc[rt][ct], 0, 0, 0);
    }
  }
  #pragma unroll
  for (int ct = 0; ct < 2; ct++) {
    int n = c0w + ct * 16 + l16;
    float b1v = b1[n];
    #pragma unroll
    for (int rt = 0; rt < 2; rt++)
      #pragma unroll
      for (int r = 0; r < 4; r++)
        ts[(rt * 16 + quad * 4 + r) * AS_STRIDE + n] = f2bf1(acc[rt][ct][r] + b1v);
  }
  __syncthreads();

  { // LN + SiLU in place (bf16); 8 threads/row
    int row = tid >> 3, sub = tid & 7;
    float s = 0.f, sq = 0.f, vals[16];
    #pragma unroll
    for (int i = 0; i < 16; i++) {
      float v = bf2f(ts[row * AS_STRIDE + sub + i * 8]);
      vals[i] = v; s += v; sq += v * v;
    }
    s += __shfl_xor(s, 1); sq += __shfl_xor(sq, 1);
    s += __shfl_xor(s, 2); sq += __shfl_xor(sq, 2);
    s += __shfl_xor(s, 4); sq += __shfl_xor(sq, 4);
    float mean = s * (1.f / 128.f);
    float rstd = rsq_f(sq * (1.f / 128.f) - mean * mean + 1e-5f);
    #pragma unroll
    for (int i = 0; i < 16; i++) {
      int c = sub + i * 8;
      float a = (vals[i] - mean) * rstd * g[c] + be[c];
      ts[row * AS_STRIDE + c] = f2bf1(silu_f(a));
    }
  }
  __syncthreads();

  f32x4 acc2[2][2];
  #pragma unroll
  for (int rt = 0; rt < 2; rt++)
    #pragma unroll
    for (int ct = 0; ct < 2; ct++)
      acc2[rt][ct] = (f32x4){0.f, 0.f, 0.f, 0.f};
  #pragma unroll
  for (int kk = 0; kk < 4; kk++) {
    const int kl = kk * 32 + quad * 8;
    bf16x8 af[2];
    #pragma unroll
    for (int rt = 0; rt < 2; rt++)
      af[rt] = *(const bf16x8*)(ts + (rt * 16 + l16) * AS_STRIDE + kl);
    #pragma unroll
    for (int ct = 0; ct < 2; ct++) {
      bf16x8 bfv = *(const bf16x8*)(W2T + (size_t)(c0w + ct * 16 + l16) * 128 + kl);
      #pragma unroll
      for (int rt = 0; rt < 2; rt++)
        acc2[rt][ct] = __builtin_amdgcn_mfma_f32_16x16x32_bf16(af[rt], bfv, acc2[rt][ct], 0, 0, 0);
    }
  }
  __syncthreads();   // ts reads done; rewrite with h
  #pragma unroll
  for (int ct = 0; ct < 2; ct++) {
    int n = c0w + ct * 16 + l16;
    float b2v = b2[n];
    #pragma unroll
    for (int rt = 0; rt < 2; rt++)
      #pragma unroll
      for (int r = 0; r < 4; r++) {
        int m = rt * 16 + quad * 4 + r;
        int node = m0 + m;
        u16 hb = f2bf1(acc2[rt][ct][r] + b2v);
        ts[m * AS_STRIDE + n] = hb;
        if (node < Nn) hbf[(size_t)node * 128 + n] = hb;
      }
  }
  __syncthreads();

  { // fused hd = h@W1d + b1, then hs = h@W1s (layer 0)
    f32x4 ah[2][2];
    #pragma unroll
    for (int rt = 0; rt < 2; rt++)
      #pragma unroll
      for (int ct = 0; ct < 2; ct++)
        ah[rt][ct] = (f32x4){0.f, 0.f, 0.f, 0.f};
    #pragma unroll
    for (int kk = 0; kk < 4; kk++) {
      const int kl = kk * 32 + quad * 8;
      bf16x8 af[2];
      #pragma unroll
      for (int rt = 0; rt < 2; rt++)
        af[rt] = *(const bf16x8*)(ts + (rt * 16 + l16) * AS_STRIDE + kl);
      #pragma unroll
      for (int ct = 0; ct < 2; ct++) {
        bf16x8 bd = *(const bf16x8*)(eW1T0 + (size_t)(c0w + ct * 16 + l16) * 256 + kl);
        #pragma unroll
        for (int rt = 0; rt < 2; rt++)
          ah[rt][ct] = __builtin_amdgcn_mfma_f32_16x16x32_bf16(af[rt], bd, ah[rt][ct], 0, 0, 0);
      }
    }
    #pragma unroll
    for (int ct = 0; ct < 2; ct++) {
      int n = c0w + ct * 16 + l16;
      float b1v = eb10[n];
      #pragma unroll
      for (int rt = 0; rt < 2; rt++)
        #pragma unroll
        for (int r = 0; r < 4; r++) {
          int node = m0 + rt * 16 + quad * 4 + r;
          if (node < Nn) hd_all[(size_t)node * 128 + n] = f2bf1(ah[rt][ct][r] + b1v);
        }
    }
    #pragma unroll
    for (int rt = 0; rt < 2; rt++)
      #pragma unroll
      for (int ct = 0; ct < 2; ct++)
        ah[rt][ct] = (f32x4){0.f, 0.f, 0.f, 0.f};
    #pragma unroll
    for (int kk = 0; kk < 4; kk++) {
      const int kl = kk * 32 + quad * 8;
      bf16x8 af[2];
      #pragma unroll
      for (int rt = 0; rt < 2; rt++)
        af[rt] = *(const bf16x8*)(ts + (rt * 16 + l16) * AS_STRIDE + kl);
      #pragma unroll
      for (int ct = 0; ct < 2; ct++) {
        bf16x8 bs = *(const bf16x8*)(eW1T0 + (size_t)(c0w + ct * 16 + l16) * 256 + 128 + kl);
        #pragma unroll
        for (int rt = 0; rt < 2; rt++)
          ah[rt][ct] = __builtin_amdgcn_mfma_f32_16x16x32_bf16(af[rt], bs, ah[rt][ct], 0, 0, 0);
      }
    }
    #pragma unroll
    for (int ct = 0; ct < 2; ct++) {
      int n = c0w + ct * 16 + l16;
      #pragma unroll
      for (int rt = 0; rt < 2; rt++)
        #pragma unroll
        for (int r = 0; r < 4; r++) {
          int node = m0 + rt * 16 + quad * 4 + r;
          if (node < Nn) hs_all[(size_t)node * 128 + n] = f2bf1(ah[rt][ct][r]);
        }
    }
  }
}

// ---------------- edge MLP: top-pinned gather prefetch + MFMA ea-term --------
__global__ __launch_bounds__(256, 4)
void edge_mlp_kernel(const int* __restrict__ ssrc, const int* __restrict__ sdst,
                     const float* __restrict__ pos,
                     const u16* __restrict__ hd_all, const u16* __restrict__ hs_all,
                     const u16* __restrict__ w1cT,  // [128][32] bf16
                     const float* __restrict__ g, const float* __restrict__ be,
                     const u16* __restrict__ W2T,   // [128][128] bf16
                     const float* __restrict__ b2,
                     float* __restrict__ aggr) {
  __shared__ int s_dst[64];
  __shared__ __align__(16) u16 s_eaA[64 * 40];        // ea feats (K padded 32)
  __shared__ __align__(16) u16 s_t[64 * AS_STRIDE];   // t_ea -> u
  __shared__ __align__(16) u16 s_msg[128 * 68];       // col-major bf16 msg
  // ~40.2 KB -> pins residency at 4 blocks/CU (r4 lesson: more blocks thrash L2)

  const int tid = threadIdx.x;
  // XCD swizzle: consecutive-dst chunks stay on one XCD (hw: block -> XCD via %8)
  const int bid = blockIdx.x;
  const int e0 = ((bid & 7) * (gridDim.x >> 3) + (bid >> 3)) * 64;
  const int w = tid >> 6, lane = tid & 63, quad = lane >> 4, l16 = lane & 15;
  const int c0w = w * 32;
  const int rg = tid >> 4, cg = tid & 15;
  const int c0 = cg * 8;

  // ---- prefetch ALL phase-A gathers at kernel top; fence pins issue order ----
  int pdst[4], psrc[4];
  #pragma unroll
  for (int rr = 0; rr < 4; rr++) {
    pdst[rr] = sdst[e0 + rg * 4 + rr];
    psrc[rr] = ssrc[e0 + rg * 4 + rr];
  }
  uint4 hd4[4], hs4[4];
  #pragma unroll
  for (int rr = 0; rr < 4; rr++) {
    hd4[rr] = *(const uint4*)(hd_all + (size_t)pdst[rr] * 128 + c0);
    hs4[rr] = *(const uint4*)(hs_all + (size_t)psrc[rr] * 128 + c0);
  }
  asm volatile("" ::: "memory");  // compiler fence: loads cannot sink below

  if (tid < 64) {
    int src = ssrc[e0 + tid], dst = sdst[e0 + tid];
    s_dst[tid] = dst;
    float dx = pos[dst * 3 + 0] - pos[src * 3 + 0];
    float dy = pos[dst * 3 + 1] - pos[src * 3 + 1];
    float dz = pos[dst * 3 + 2] - pos[src * 3 + 2];
    float dist = sqrtf(dx * dx + dy * dy + dz * dz) + 1e-8f;
    float inv = __builtin_amdgcn_rcpf(dist);
    union { u16 us[40]; uint4 v[5]; } pk;
    #pragma unroll
    for (int k = 0; k < 40; k++) pk.us[k] = 0;
    pk.us[0] = f2bf1(dist);
    pk.us[1] = f2bf1(dx * inv); pk.us[2] = f2bf1(dy * inv); pk.us[3] = f2bf1(dz * inv);
    pk.us[4] = f2bf1(__builtin_amdgcn_rcpf(dist * dist + 1e-6f));
    #pragma unroll
    for (int k = 0; k < 5; k++) *(uint4*)(s_eaA + tid * 40 + k * 8) = pk.v[k];
  }
  __syncthreads();

  { // ea @ w1c on the MFMA pipe -> t_ea in s_t (bf16 row-major)
    f32x4 ae[4][2];
    #pragma unroll
    for (int rt = 0; rt < 4; rt++)
      #pragma unroll
      for (int ct = 0; ct < 2; ct++)
        ae[rt][ct] = (f32x4){0.f, 0.f, 0.f, 0.f};
    const int kl = quad * 8;
    bf16x8 afe[4];
    #pragma unroll
    for (int rt = 0; rt < 4; rt++)
      afe[rt] = *(const bf16x8*)(s_eaA + (rt * 16 + l16) * 40 + kl);
    #pragma unroll
    for (int ct = 0; ct < 2; ct++) {
      bf16x8 bw = *(const bf16x8*)(w1cT + (c0w + ct * 16 + l16) * 32 + kl);
      #pragma unroll
      for (int rt = 0; rt < 4; rt++)
        ae[rt][ct] = __builtin_amdgcn_mfma_f32_16x16x32_bf16(afe[rt], bw, ae[rt][ct], 0, 0, 0);
    }
    #pragma unroll
    for (int ct = 0; ct < 2; ct++) {
      int n = c0w + ct * 16 + l16;
      #pragma unroll
      for (int rt = 0; rt < 4; rt++)
        #pragma unroll
        for (int r = 0; r < 4; r++)
          s_t[(rt * 16 + quad * 4 + r) * AS_STRIDE + n] = f2bf1(ae[rt][ct][r]);
    }
  }
  __syncthreads();

  { // phase A: t = t_ea + hd[dst] + hs[src]; LN+SiLU -> u in s_t
    f32x2 g2[4], be2[4];
    {
      f32x4 ga = *(const f32x4*)(g + c0), gb = *(const f32x4*)(g + c0 + 4);
      f32x4 ba = *(const f32x4*)(be + c0), bb = *(const f32x4*)(be + c0 + 4);
      g2[0] = (f32x2){ga[0], ga[1]}; g2[1] = (f32x2){ga[2], ga[3]};
      g2[2] = (f32x2){gb[0], gb[1]}; g2[3] = (f32x2){gb[2], gb[3]};
      be2[0] = (f32x2){ba[0], ba[1]}; be2[1] = (f32x2){ba[2], ba[3]};
      be2[2] = (f32x2){bb[0], bb[1]}; be2[3] = (f32x2){bb[2], bb[3]};
    }
    #pragma unroll
    for (int rr = 0; rr < 4; rr++) {
      int m = rg * 4 + rr;
      uint4 te4 = *(const uint4*)(s_t + m * AS_STRIDE + c0);
      u32 hp[4] = {hd4[rr].x, hd4[rr].y, hd4[rr].z, hd4[rr].w};
      u32 sp[4] = {hs4[rr].x, hs4[rr].y, hs4[rr].z, hs4[rr].w};
      u32 tp[4] = {te4.x, te4.y, te4.z, te4.w};
      f32x2 t2[4], sm2 = (f32x2){0.f, 0.f}, sq2 = (f32x2){0.f, 0.f};
      #pragma unroll
      for (int p = 0; p < 4; p++) {
        t2[p] = unpk2(hp[p]) + unpk2(sp[p]) + unpk2(tp[p]);
        sm2 += t2[p];
        sq2 += t2[p] * t2[p];
      }
      float sm = sm2[0] + sm2[1], sq = sq2[0] + sq2[1];
      sm += __shfl_xor(sm, 1);  sq += __shfl_xor(sq, 1);
      sm += __shfl_xor(sm, 2);  sq += __shfl_xor(sq, 2);
      sm += __shfl_xor(sm, 4);  sq += __shfl_xor(sq, 4);
      sm += __shfl_xor(sm, 8);  sq += __shfl_xor(sq, 8);
      float mean = sm * (1.f / 128.f);
      float rstd = rsq_f(sq * (1.f / 128.f) - mean * mean + 1e-5f);
      f32x2 sc = (f32x2){rstd, rstd};
      f32x2 ofs = (f32x2){-mean * rstd, -mean * rstd};
      float o[8];
      #pragma unroll
      for (int p = 0; p < 4; p++) {
        f32x2 a = t2[p] * sc + ofs;
        a = a * g2[p] + be2[p];
        o[2 * p]     = silu_f(a[0]);
        o[2 * p + 1] = silu_f(a[1]);
      }
      uint4 st;
      st.x = cvt2bf(o[0], o[1]); st.y = cvt2bf(o[2], o[3]);
      st.z = cvt2bf(o[4], o[5]); st.w = cvt2bf(o[6], o[7]);
      *(uint4*)(s_t + m * AS_STRIDE + c0) = st;
    }
  }
  __syncthreads();

  f32x4 acc2[4][2];
  #pragma unroll
  for (int rt = 0; rt < 4; rt++)
    #pragma unroll
    for (int ct = 0; ct < 2; ct++)
      acc2[rt][ct] = (f32x4){0.f, 0.f, 0.f, 0.f};

  #pragma unroll
  for (int kk = 0; kk < 4; kk++) {               // K=128
    const int kl = kk * 32 + quad * 8;
    bf16x8 af[4];
    #pragma unroll
    for (int rt = 0; rt < 4; rt++)
      af[rt] = *(const bf16x8*)(s_t + (rt * 16 + l16) * AS_STRIDE + kl);
    #pragma unroll
    for (int ct = 0; ct < 2; ct++) {
      bf16x8 bfv = *(const bf16x8*)(W2T + (size_t)(c0w + ct * 16 + l16) * 128 + kl);
      #pragma unroll
      for (int rt = 0; rt < 4; rt++)
        acc2[rt][ct] = __builtin_amdgcn_mfma_f32_16x16x32_bf16(af[rt], bfv, acc2[rt][ct], 0, 0, 0);
    }
  }

  #pragma unroll
  for (int ct = 0; ct < 2; ct++) {
    int n = c0w + ct * 16 + l16;
    float b2v = b2[n];
    #pragma unroll
    for (int rt = 0; rt < 4; rt++) {
      int mb = rt * 16 + quad * 4;
      uint2 st;
      st.x = cvt2bf(acc2[rt][ct][0] + b2v, acc2[rt][ct][1] + b2v);
      st.y = cvt2bf(acc2[rt][ct][2] + b2v, acc2[rt][ct][3] + b2v);
      *(uint2*)(s_msg + n * 68 + mb) = st;
    }
  }
  __syncthreads();

  { // segmented column-sum over sorted dst runs (b64 reads, f32 accumulate)
    int c = tid & 127, q = tid >> 7;
    int r0 = q * 32;
    const u16* mp = s_msg + c * 68 + r0;
    float run = 0.f; int cur = s_dst[r0];
    #pragma unroll
    for (int i = 0; i < 8; i++) {
      uint2 pr = *(const uint2*)(mp + 4 * i);
      union { u32 u; float f; } va, vb, vc, vd;
      va.u = pr.x << 16; vb.u = pr.x & 0xffff0000u;
      vc.u = pr.y << 16; vd.u = pr.y & 0xffff0000u;
      int rb = r0 + 4 * i;
      int d0 = s_dst[rb], d1 = s_dst[rb + 1], d2 = s_dst[rb + 2], d3 = s_dst[rb + 3];
      if (d0 != cur) { atomicAdd(&aggr[(size_t)cur * 128 + c], run); run = 0.f; cur = d0; }
      run += va.f;
      if (d1 != cur) { atomicAdd(&aggr[(size_t)cur * 128 + c], run); run = 0.f; cur = d1; }
      run += vb.f;
      if (d2 != cur) { atomicAdd(&aggr[(size_t)cur * 128 + c], run); run = 0.f; cur = d2; }
      run += vc.f;
      if (d3 != cur) { atomicAdd(&aggr[(size_t)cur * 128 + c], run); run = 0.f; cur = d3; }
      run += vd.f;
    }
    atomicAdd(&aggr[(size_t)cur * 128 + c], run);
  }
}

// -- node MLP (32-row tiles) + residual + LN + fused next hd/hs OR decoder ----
__global__ __launch_bounds__(256, 6)
void node_mlp_kernel(u16* __restrict__ hbf, float* __restrict__ aggr,
                     const u16* __restrict__ W1T, const float* __restrict__ b1,
                     const float* __restrict__ g, const float* __restrict__ be,
                     const u16* __restrict__ W2T, const float* __restrict__ b2,
                     const float* __restrict__ lng, const float* __restrict__ lnb,
                     const u16* __restrict__ W1Tn, const float* __restrict__ b1n,
                     u16* __restrict__ hd_all, u16* __restrict__ hs_all,
                     const float* __restrict__ x,
                     const u16* __restrict__ dW1T, const float* __restrict__ db1,
                     const u16* __restrict__ dW2T, const float* __restrict__ db2,
                     const u16* __restrict__ dW3T, const float* __restrict__ db3,
                     float* __restrict__ out,
                     int Nn) {
  __shared__ __align__(16) u16 As[64 * AS_STRIDE];  // 17,408 B (h 32 rows | aggr 32 rows)
  u16* t_su = As;                    // [32][136] (reused after MFMA1)
  u16* u_su = As + 32 * AS_STRIDE;   // [32][136] (overwrites aggr region)

  const int tid = threadIdx.x;
  const int m0 = blockIdx.x * 32;
  const int w = tid >> 6, lane = tid & 63, quad = lane >> 4, l16 = lane & 15;
  const int c0w = w * 32;

  { // stage h (bf16 copy) + aggr (f32 -> bf16), then zero aggr for next layer
    int r = tid >> 4, c8 = (tid & 15) * 8;
    const float4 z4 = {0.f, 0.f, 0.f, 0.f};
    #pragma unroll
    for (int rp = 0; rp < 2; rp++) {
      int m = rp * 16 + r;
      int node = m0 + m; if (node >= Nn) node = Nn - 1;
      *(uint4*)(As + m * AS_STRIDE + c8) = *(const uint4*)(hbf + (size_t)node * 128 + c8);
      float* ap = aggr + (size_t)node * 128 + c8;
      float4 f0 = *(const float4*)ap;
      float4 f1 = *(const float4*)(ap + 4);
      uint4 pk;
      pk.x = cvt2bf(f0.x, f0.y); pk.y = cvt2bf(f0.z, f0.w);
      pk.z = cvt2bf(f1.x, f1.y); pk.w = cvt2bf(f1.z, f1.w);
      *(uint4*)(As + (32 + m) * AS_STRIDE + c8) = pk;
      *(float4*)ap = z4;
      *(float4*)(ap + 4) = z4;
    }
  }
  __syncthreads();

  f32x4 acc[2][2];
  #pragma unroll
  for (int rt = 0; rt < 2; rt++)
    #pragma unroll
    for (int ct = 0; ct < 2; ct++)
      acc[rt][ct] = (f32x4){0.f, 0.f, 0.f, 0.f};

  #pragma unroll
  for (int kk = 0; kk < 8; kk++) {
    const u16* Ab = As + (kk < 4 ? 0 : 32 * AS_STRIDE);
    const int kl = (kk & 3) * 32 + quad * 8;
    bf16x8 af[2];
    #pragma unroll
    for (int rt = 0; rt < 2; rt++)
      af[rt] = *(const bf16x8*)(Ab + (rt * 16 + l16) * AS_STRIDE + kl);
    const int kg = kk * 32 + quad * 8;
    #pragma unroll
    for (int ct = 0; ct < 2; ct++) {
      bf16x8 bfv = *(const bf16x8*)(W1T + (size_t)(c0w + ct * 16 + l16) * 256 + kg);
      #pragma unroll
      for (int rt = 0; rt < 2; rt++)
        acc[rt][ct] = __builtin_amdgcn_mfma_f32_16x16x32_bf16(af[rt], bfv, acc[rt][ct], 0, 0, 0);
    }
  }

  float b1v[2];
  #pragma unroll
  for (int ct = 0; ct < 2; ct++) b1v[ct] = b1[c0w + ct * 16 + l16];
  __syncthreads();

  #pragma unroll
  for (int rt = 0; rt < 2; rt++)
    #pragma unroll
    for (int ct = 0; ct < 2; ct++) {
      int n = c0w + ct * 16 + l16;
      #pragma unroll
      for (int r = 0; r < 4; r++)
        t_su[(rt * 16 + quad * 4 + r) * AS_STRIDE + n] = f2bf1(acc[rt][ct][r] + b1v[ct]);
    }
  __syncthreads();

  { // inner LN + SiLU: read t_su, write u_su; 8 threads/row
    int row = tid >> 3, sub = tid & 7;
    float s = 0.f, sq = 0.f, vals[16];
    #pragma unroll
    for (int i = 0; i < 16; i++) {
      float v = bf2f(t_su[row * AS_STRIDE + sub + i * 8]);
      vals[i] = v; s += v; sq += v * v;
    }
    s += __shfl_xor(s, 1); sq += __shfl_xor(sq, 1);
    s += __shfl_xor(s, 2); sq += __shfl_xor(sq, 2);
    s += __shfl_xor(s, 4); sq += __shfl_xor(sq, 4);
    float mean = s * (1.f / 128.f);
    float rstd = rsq_f(sq * (1.f / 128.f) - mean * mean + 1e-5f);
    #pragma unroll
    for (int i = 0; i < 16; i++) {
      int c = sub + i * 8;
      float a = (vals[i] - mean) * rstd * g[c] + be[c];
      u_su[row * AS_STRIDE + c] = f2bf1(silu_f(a));
    }
  }
  __syncthreads();

  f32x4 acc2[2][2];
  #pragma unroll
  for (int rt = 0; rt < 2; rt++)
    #pragma unroll
    for (int ct = 0; ct < 2; ct++)
      acc2[rt][ct] = (f32x4){0.f, 0.f, 0.f, 0.f};

  #pragma unroll
  for (int kk = 0; kk < 4; kk++) {
    const int kl = kk * 32 + quad * 8;
    bf16x8 af[2];
    #pragma unroll
    for (int rt = 0; rt < 2; rt++)
      af[rt] = *(const bf16x8*)(u_su + (rt * 16 + l16) * AS_STRIDE + kl);
    #pragma unroll
    for (int ct = 0; ct < 2; ct++) {
      bf16x8 bfv = *(const bf16x8*)(W2T + (size_t)(c0w + ct * 16 + l16) * 128 + kl);
      #pragma unroll
      for (int rt = 0; rt < 2; rt++)
        acc2[rt][ct] = __builtin_amdgcn_mfma_f32_16x16x32_bf16(af[rt], bfv, acc2[rt][ct], 0, 0, 0);
    }
  }
  __syncthreads();

  #pragma unroll
  for (int ct = 0; ct < 2; ct++) {
    int n = c0w + ct * 16 + l16;
    float b2v = b2[n];
    #pragma unroll
    for (int rt = 0; rt < 2; rt++)
      #pragma unroll
      for (int r = 0; r < 4; r++) {
        int m = rt * 16 + quad * 4 + r;
        int node = m0 + m; if (node >= Nn) node = Nn - 1;
        t_su[m * AS_STRIDE + n] =
            f2bf1(acc2[rt][ct][r] + b2v + bf2f(hbf[(size_t)node * 128 + n]));
      }
  }
  __syncthreads();

  { // outer LN -> hbf and back into t_su (A-layout h); 8 threads/row
    int row = tid >> 3, sub = tid & 7;
    int node = m0 + row;
    float s = 0.f, sq = 0.f, vals[16];
    #pragma unroll
    for (int i = 0; i < 16; i++) {
      float v = bf2f(t_su[row * AS_STRIDE + sub + i * 8]);
      vals[i] = v; s += v; sq += v * v;
    }
    s += __shfl_xor(s, 1); sq += __shfl_xor(sq, 1);
    s += __shfl_xor(s, 2); sq += __shfl_xor(sq, 2);
    s += __shfl_xor(s, 4); sq += __shfl_xor(sq, 4);
    float mean = s * (1.f / 128.f);
    float rstd = rsq_f(sq * (1.f / 128.f) - mean * mean + 1e-5f);
    #pragma unroll
    for (int i = 0; i < 16; i++) {
      int c = sub + i * 8;
      float v = (vals[i] - mean) * rstd * lng[c] + lnb[c];
      u16 hb = f2bf1(v);
      t_su[row * AS_STRIDE + c] = hb;
      if (node < Nn) hbf[(size_t)node * 128 + c] = hb;
    }
  }

  if (W1Tn != nullptr) { // fused next-layer hd = h@W1d + b1, hs = h@W1s
    __syncthreads();
    f32x4 ah[2][2];
    #pragma unroll
    for (int rt = 0; rt < 2; rt++)
      #pragma unroll
      for (int ct = 0; ct < 2; ct++)
        ah[rt][ct] = (f32x4){0.f, 0.f, 0.f, 0.f};
    #pragma unroll
    for (int kk = 0; kk < 4; kk++) {
      const int kl = kk * 32 + quad * 8;
      bf16x8 af[2];
      #pragma unroll
      for (int rt = 0; rt < 2; rt++)
        af[rt] = *(const bf16x8*)(t_su + (rt * 16 + l16) * AS_STRIDE + kl);
      #pragma unroll
      for (int ct = 0; ct < 2; ct++) {
        bf16x8 bd = *(const bf16x8*)(W1Tn + (size_t)(c0w + ct * 16 + l16) * 256 + kl);
        #pragma unroll
        for (int rt = 0; rt < 2; rt++)
          ah[rt][ct] = __builtin_amdgcn_mfma_f32_16x16x32_bf16(af[rt], bd, ah[rt][ct], 0, 0, 0);
      }
    }
    #pragma unroll
    for (int ct = 0; ct < 2; ct++) {
      int n = c0w + ct * 16 + l16;
      float bv = b1n[n];
      #pragma unroll
      for (int rt = 0; rt < 2; rt++)
        #pragma unroll
        for (int r = 0; r < 4; r++) {
          int node = m0 + rt * 16 + quad * 4 + r;
          if (node < Nn) hd_all[(size_t)node * 128 + n] = f2bf1(ah[rt][ct][r] + bv);
        }
    }
    #pragma unroll
    for (int rt = 0; rt < 2; rt++)
      #pragma unroll
      for (int ct = 0; ct < 2; ct++)
        ah[rt][ct] = (f32x4){0.f, 0.f, 0.f, 0.f};
    #pragma unroll
    for (int kk = 0; kk < 4; kk++) {
      const int kl = kk * 32 + quad * 8;
      bf16x8 af[2];
      #pragma unroll
      for (int rt = 0; rt < 2; rt++)
        af[rt] = *(const bf16x8*)(t_su + (rt * 16 + l16) * AS_STRIDE + kl);
      #pragma unroll
      for (int ct = 0; ct < 2; ct++) {
        bf16x8 bs = *(const bf16x8*)(W1Tn + (size_t)(c0w + ct * 16 + l16) * 256 + 128 + kl);
        #pragma unroll
        for (int rt = 0; rt < 2; rt++)
          ah[rt][ct] = __builtin_amdgcn_mfma_f32_16x16x32_bf16(af[rt], bs, ah[rt][ct], 0, 0, 0);
      }
    }
    #pragma unroll
    for (int ct = 0; ct < 2; ct++) {
      int n = c0w + ct * 16 + l16;
      #pragma unroll
      for (int rt = 0; rt < 2; rt++)
        #pragma unroll
        for (int r = 0; r < 4; r++) {
          int node = m0 + rt * 16 + quad * 4 + r;
          if (node < Nn) hs_all[(size_t)node * 128 + n] = f2bf1(ah[rt][ct][r]);
        }
    }
  }

  if (dW1T != nullptr) { // fused decoder (layer 2): h in t_su (A-layout)
    __syncthreads();
    f32x4 da[2][2];
    #pragma unroll
    for (int rt = 0; rt < 2; rt++)
      #pragma unroll
      for (int ct = 0; ct < 2; ct++)
        da[rt][ct] = (f32x4){0.f, 0.f, 0.f, 0.f};
    #pragma unroll
    for (int kk = 0; kk < 4; kk++) {
      const int kl = kk * 32 + quad * 8;
      bf16x8 af[2];
      #pragma unroll
      for (int rt = 0; rt < 2; rt++)
        af[rt] = *(const bf16x8*)(t_su + (rt * 16 + l16) * AS_STRIDE + kl);
      #pragma unroll
      for (int ct = 0; ct < 2; ct++) {
        bf16x8 bfv = *(const bf16x8*)(dW1T + (size_t)(c0w + ct * 16 + l16) * 128 + kl);
        #pragma unroll
        for (int rt = 0; rt < 2; rt++)
          da[rt][ct] = __builtin_amdgcn_mfma_f32_16x16x32_bf16(af[rt], bfv, da[rt][ct], 0, 0, 0);
      }
    }
    __syncthreads();
    #pragma unroll
    for (int ct = 0; ct < 2; ct++) {
      int n = c0w + ct * 16 + l16;
      float bv = db1[n];
      #pragma unroll
      for (int rt = 0; rt < 2; rt++)
        #pragma unroll
        for (int r = 0; r < 4; r++)
          u_su[(rt * 16 + quad * 4 + r) * AS_STRIDE + n] = f2bf1(silu_f(da[rt][ct][r] + bv));
    }
    __syncthreads();
    { // dec L2: 64 cols, wave covers 16; u2 overwrites t_su region (stride 72)
      const int c0b = w * 16;
      f32x4 a2[2];
      #pragma unroll
      for (int rt = 0; rt < 2; rt++) a2[rt] = (f32x4){0.f, 0.f, 0.f, 0.f};
      #pragma unroll
      for (int kk = 0; kk < 4; kk++) {
        const int kl = kk * 32 + quad * 8;
        bf16x8 af[2];
        #pragma unroll
        for (int rt = 0; rt < 2; rt++)
          af[rt] = *(const bf16x8*)(u_su + (rt * 16 + l16) * AS_STRIDE + kl);
        bf16x8 bfv = *(const bf16x8*)(dW2T + (size_t)(c0b + l16) * 128 + kl);
        #pragma unroll
        for (int rt = 0; rt < 2; rt++)
          a2[rt] = __builtin_amdgcn_mfma_f32_16x16x32_bf16(af[rt], bfv, a2[rt], 0, 0, 0);
      }
      float bv = db2[c0b + l16];
      #pragma unroll
      for (int rt = 0; rt < 2; rt++)
        #pragma unroll
        for (int r = 0; r < 4; r++)
          t_su[(rt * 16 + quad * 4 + r) * 72 + c0b + l16] = f2bf1(silu_f(a2[rt][r] + bv));
    }
    __syncthreads();
    if (w == 0) { // dec L3: 6 cols (padded 16), K=64
      f32x4 a3[2];
      #pragma unroll
      for (int rt = 0; rt < 2; rt++) a3[rt] = (f32x4){0.f, 0.f, 0.f, 0.f};
      #pragma unroll
      for (int kk = 0; kk < 2; kk++) {
        const int kl = kk * 32 + quad * 8;
        bf16x8 af[2];
        #pragma unroll
        for (int rt = 0; rt < 2; rt++)
          af[rt] = *(const bf16x8*)(t_su + (rt * 16 + l16) * 72 + kl);
        bf16x8 bfv = *(const bf16x8*)(dW3T + l16 * 64 + kl);
        #pragma unroll
        for (int rt = 0; rt < 2; rt++)
          a3[rt] = __builtin_amdgcn_mfma_f32_16x16x32_bf16(af[rt], bfv, a3[rt], 0, 0, 0);
      }
      if (l16 < 6) {
        float bv = db3[l16];
        #pragma unroll
        for (int rt = 0; rt < 2; rt++)
          #pragma unroll
          for (int r = 0; r < 4; r++) {
            int node = m0 + rt * 16 + quad * 4 + r;
            if (node < Nn)
              out[(size_t)node * 6 + l16] = a3[rt][r] + bv + x[node * 7 + l16];
          }
      }
    }
  }
}

// ---------------- host launcher ----------------------------------------------
extern "C" void kernel_launch(void* const* d_in, const int* in_sizes, int n_in,
                              void* d_out, int out_size, void* d_ws, size_t ws_size,
                              hipStream_t stream) {
  const float* x      = (const float*)d_in[0];
  const float* pos    = (const float*)d_in[1];
  const int*   eidx   = (const int*)d_in[2];
  const float* enc_w1 = (const float*)d_in[3];
  const float* enc_b1 = (const float*)d_in[4];
  const float* enc_g  = (const float*)d_in[5];
  const float* enc_be = (const float*)d_in[6];
  const float* enc_w2 = (const float*)d_in[7];
  const float* enc_b2 = (const float*)d_in[8];
  const float* e_w1   = (const float*)d_in[9];
  const float* e_b1   = (const float*)d_in[10];
  const float* e_g    = (const float*)d_in[11];
  const float* e_be   = (const float*)d_in[12];
  const float* e_w2   = (const float*)d_in[13];
  const float* e_b2   = (const float*)d_in[14];
  const float* n_w1   = (const float*)d_in[15];
  const float* n_b1   = (const float*)d_in[16];
  const float* n_g    = (const float*)d_in[17];
  const float* n_be   = (const float*)d_in[18];
  const float* n_w2   = (const float*)d_in[19];
  const float* n_b2   = (const float*)d_in[20];
  const float* ln_g   = (const float*)d_in[21];
  const float* ln_b   = (const float*)d_in[22];
  const float* dec_w1 = (const float*)d_in[23];
  const float* dec_b1 = (const float*)d_in[24];
  const float* dec_w2 = (const float*)d_in[25];
  const float* dec_b2 = (const float*)d_in[26];
  const float* dec_w3 = (const float*)d_in[27];
  const float* dec_b3 = (const float*)d_in[28];

  const int N = in_sizes[0] / 7;          // 50000
  const int E = in_sizes[2] / 2;          // 1600000

  char* ws = (char*)d_ws;
  size_t off = 0;
  u16*   hbf    = (u16*)(ws + off);   off += (size_t)N * 128 * 2;
  u16*   hd_all = (u16*)(ws + off);   off += (size_t)N * 128 * 2;
  u16*   hs_all = (u16*)(ws + off);   off += (size_t)N * 128 * 2;
  float* aggr   = (float*)(ws + off); off += (size_t)N * 128 * 4;
  u16* eW1T = (u16*)(ws + off); off += 3 * 128 * 256 * 2;
  u16* eW2T = (u16*)(ws + off); off += 3 * 128 * 128 * 2;
  u16* nW1T = (u16*)(ws + off); off += 3 * 128 * 256 * 2;
  u16* nW2T = (u16*)(ws + off); off += 3 * 128 * 128 * 2;
  u16* encW1T = (u16*)(ws + off); off += 128 * 32 * 2;
  u16* encW2T = (u16*)(ws + off); off += 128 * 128 * 2;
  u16* decW1T = (u16*)(ws + off); off += 128 * 128 * 2;
  u16* decW2T = (u16*)(ws + off); off += 64 * 128 * 2;
  u16* decW3T = (u16*)(ws + off); off += 16 * 64 * 2;
  u16* eW1cT  = (u16*)(ws + off); off += 3 * 128 * 32 * 2;
  int* cnt    = (int*)(ws + off); off += (size_t)N * 4;
  int* cursor = (int*)(ws + off); off += (size_t)N * 4;
  int* ssrc   = (int*)(ws + off); off += (size_t)E * 4;
  int* sdst   = (int*)(ws + off); off += (size_t)E * 4;

  // sort edges by dst once (reused across all 3 layers)
  hipMemsetAsync(cnt, 0, (size_t)N * 4, stream);
  edge_hist<<<(E + 255) / 256, 256, 0, stream>>>(eidx + E, E, cnt);
  scan_kernel<<<1, 1024, 0, stream>>>(cnt, cursor, N);
  edge_scatter<<<(E + 255) / 256, 256, 0, stream>>>(eidx, eidx + E, E, cursor, ssrc, sdst);

  prep_weights<<<1152, 256, 0, stream>>>(e_w1, e_w2, n_w1, n_w2, eW1T, eW2T, nW1T, nW2T);
  prep_weights2<<<228, 256, 0, stream>>>(enc_w1, enc_w2, dec_w1, dec_w2, dec_w3, e_w1,
                                         encW1T, encW2T, decW1T, decW2T, decW3T, eW1cT);

  // zero aggr ONCE; node_mlp re-zeroes its rows for the next layer after reading
  hipMemsetAsync(aggr, 0, (size_t)N * 128 * 4, stream);

  const int nblk32 = (N + 31) / 32;   // 1563: 2x blocks -> 2x co-residency vs 64-row tiles
  encoder_mfma<<<nblk32, 256, 0, stream>>>(x, encW1T, enc_b1, enc_g, enc_be, encW2T, enc_b2,
                                           eW1T, e_b1, hbf, hd_all, hs_all, N);

  for (int l = 0; l < 3; l++) {
    edge_mlp_kernel<<<E / 64, 256, 0, stream>>>(
        ssrc, sdst, pos, hd_all, hs_all,
        eW1cT + (size_t)l * 4096,
        e_g + l * 128, e_be + l * 128,
        eW2T + (size_t)l * 128 * 128, e_b2 + l * 128, aggr);
    const u16* W1Tn = (l < 2) ? (eW1T + (size_t)(l + 1) * 128 * 256) : (const u16*)nullptr;
    const bool last = (l == 2);
    node_mlp_kernel<<<nblk32, 256, 0, stream>>>(
        hbf, aggr,
        nW1T + (size_t)l * 128 * 256, n_b1 + l * 128, n_g + l * 128, n_be + l * 128,
        nW2T + (size_t)l * 128 * 128, n_b2 + l * 128,
        ln_g + l * 128, ln_b + l * 128,
        W1Tn, e_b1 + ((l + 1) % 3) * 128, hd_all, hs_all,
        x,
        last ? decW1T : (const u16*)nullptr, dec_b1,
        last ? decW2T : (const u16*)nullptr, dec_b2,
        last ? decW3T : (const u16*)nullptr, dec_b3,
        (float*)d_out, N);
  }
}

// Round 12
// 1222.220 us; speedup vs baseline: 1.0380x; 1.0380x over previous
//
#include <hip/hip_runtime.h>

typedef unsigned short u16;
typedef unsigned int u32;
typedef __bf16 bf16x8 __attribute__((ext_vector_type(8)));
typedef float f32x4 __attribute__((ext_vector_type(4)));
typedef float f32x2 __attribute__((ext_vector_type(2)));

#define AS_STRIDE 136   // bf16 elems per LDS A-row (128 + 8 pad; 16B-aligned rows)

__device__ __forceinline__ u16 f2bf1(float f) {
  union { __bf16 h; u16 u; } c; c.h = (__bf16)f; return c.u;
}
__device__ __forceinline__ u32 cvt2bf(float a, float b) {
  union { __bf16 h[2]; u32 u; } c; c.h[0] = (__bf16)a; c.h[1] = (__bf16)b; return c.u;
}
__device__ __forceinline__ float bf2f(u16 u) {
  union { u32 u; float f; } v; v.u = ((u32)u) << 16; return v.f;
}
// silu via v_rcp_f32 (2 ops) instead of IEEE f32 divide (~10-op sequence)
__device__ __forceinline__ float silu_f(float a) {
  return a * __builtin_amdgcn_rcpf(1.f + __expf(-a));
}
__device__ __forceinline__ float rsq_f(float x) {
  return __builtin_amdgcn_rsqf(x);
}
__device__ __forceinline__ f32x2 unpk2(u32 p) {
  union { u32 u; float f; } a, b;
  a.u = p << 16; b.u = p & 0xffff0000u;
  return (f32x2){a.f, b.f};
}

// ---------------- edge sort by dst (counting sort, once per call) ------------
__global__ void edge_hist(const int* __restrict__ edst, int E, int* __restrict__ cnt) {
  int i = blockIdx.x * blockDim.x + threadIdx.x;
  if (i < E) atomicAdd(&cnt[edst[i]], 1);
}

__global__ __launch_bounds__(1024)
void scan_kernel(const int* __restrict__ cnt, int* __restrict__ cursor, int Nn) {
  __shared__ int part[1024];
  int t = threadIdx.x;
  int per = (Nn + 1023) / 1024;
  int b = t * per;
  int s = 0;
  for (int i = 0; i < per; i++) { int idx = b + i; if (idx < Nn) s += cnt[idx]; }
  part[t] = s;
  __syncthreads();
  for (int d = 1; d < 1024; d <<= 1) {
    int v = (t >= d) ? part[t - d] : 0;
    __syncthreads();
    part[t] += v;
    __syncthreads();
  }
  int excl = (t == 0) ? 0 : part[t - 1];
  for (int i = 0; i < per; i++) {
    int idx = b + i;
    if (idx < Nn) { cursor[idx] = excl; excl += cnt[idx]; }
  }
}

__global__ void edge_scatter(const int* __restrict__ esrc, const int* __restrict__ edst,
                             int E, int* __restrict__ cursor,
                             int* __restrict__ ssrc, int* __restrict__ sdst) {
  int i = blockIdx.x * blockDim.x + threadIdx.x;
  if (i < E) {
    int d = edst[i];
    int p = atomicAdd(&cursor[d], 1);
    ssrc[p] = esrc[i];
    sdst[p] = d;
  }
}

// ---------------- weight prep: transpose + bf16-cast -------------------------
__global__ void prep_weights(const float* __restrict__ e_w1, const float* __restrict__ e_w2,
                             const float* __restrict__ n_w1, const float* __restrict__ n_w2,
                             u16* __restrict__ eW1T, u16* __restrict__ eW2T,
                             u16* __restrict__ nW1T, u16* __restrict__ nW2T) {
  int i = blockIdx.x * blockDim.x + threadIdx.x;
  const int s1 = 3 * 128 * 256;
  const int s2 = 3 * 128 * 128;
  if (i < s1) {
    int l = i / 32768, r = i % 32768, n = r >> 8, k = r & 255;
    eW1T[i] = f2bf1(e_w1[l * 33408 + k * 128 + n]);
  } else if (i < s1 + s2) {
    int j = i - s1; int l = j / 16384, r = j % 16384, n = r >> 7, k = r & 127;
    eW2T[j] = f2bf1(e_w2[l * 16384 + k * 128 + n]);
  } else if (i < s1 + s2 + s1) {
    int j = i - s1 - s2; int l = j / 32768, r = j % 32768, n = r >> 8, k = r & 255;
    nW1T[j] = f2bf1(n_w1[l * 32768 + k * 128 + n]);
  } else if (i < 2 * s1 + 2 * s2) {
    int j = i - 2 * s1 - s2; int l = j / 16384, r = j % 16384, n = r >> 7, k = r & 127;
    nW2T[j] = f2bf1(n_w2[l * 16384 + k * 128 + n]);
  }
}

// enc/dec weights + edge-attr weight
__global__ void prep_weights2(const float* __restrict__ enc_w1, const float* __restrict__ enc_w2,
                              const float* __restrict__ dec_w1, const float* __restrict__ dec_w2,
                              const float* __restrict__ dec_w3, const float* __restrict__ e_w1,
                              u16* __restrict__ encW1T, u16* __restrict__ encW2T,
                              u16* __restrict__ decW1T, u16* __restrict__ decW2T,
                              u16* __restrict__ decW3T, u16* __restrict__ eW1cT) {
  int i = blockIdx.x * blockDim.x + threadIdx.x;
  if (i < 4096) {
    int n = i >> 5, k = i & 31;
    encW1T[i] = (k < 7) ? f2bf1(enc_w1[k * 128 + n]) : (u16)0;
  } else if (i < 20480) {
    int j = i - 4096; int n = j >> 7, k = j & 127;
    encW2T[j] = f2bf1(enc_w2[k * 128 + n]);
  } else if (i < 36864) {
    int j = i - 20480; int n = j >> 7, k = j & 127;
    decW1T[j] = f2bf1(dec_w1[k * 128 + n]);
  } else if (i < 45056) {
    int j = i - 36864; int n = j >> 7, k = j & 127;
    decW2T[j] = f2bf1(dec_w2[k * 64 + n]);
  } else if (i < 46080) {
    int j = i - 45056; int n = j >> 6, k = j & 63;
    decW3T[j] = (n < 6) ? f2bf1(dec_w3[k * 6 + n]) : (u16)0;
  } else if (i < 58368) {
    int j = i - 46080; int l = j / 4096, r = j % 4096, n = r >> 5, k = r & 31;
    eW1cT[j] = (k < 5) ? f2bf1(e_w1[l * 33408 + (256 + k) * 128 + n]) : (u16)0;
  }
}

// ---------------- encoder (MFMA) + fused hd/hs for layer 0 -------------------
__global__ __launch_bounds__(256, 4)
void encoder_mfma(const float* __restrict__ x,
                  const u16* __restrict__ W1T,   // [128][32]
                  const float* __restrict__ b1,
                  const float* __restrict__ g, const float* __restrict__ be,
                  const u16* __restrict__ W2T,   // [128][128]
                  const float* __restrict__ b2,
                  const u16* __restrict__ eW1T0, // [128][256] layer-0 edge W1
                  const float* __restrict__ eb10,
                  u16* __restrict__ hbf, u16* __restrict__ hd_all,
                  u16* __restrict__ hs_all, int Nn) {
  __shared__ __align__(16) u16 As[64 * 40];
  __shared__ __align__(16) u16 ts[64 * AS_STRIDE];
  const int tid = threadIdx.x;
  const int m0 = blockIdx.x * 64;
  const int w = tid >> 6, lane = tid & 63, quad = lane >> 4, l16 = lane & 15;
  const int c0w = w * 32;

  if (tid < 64) {
    int node = m0 + tid; if (node >= Nn) node = Nn - 1;
    union { u16 us[32]; uint4 v[4]; } pk;
    #pragma unroll
    for (int k = 0; k < 32; k++) pk.us[k] = 0;
    #pragma unroll
    for (int k = 0; k < 7; k++) pk.us[k] = f2bf1(x[node * 7 + k]);
    #pragma unroll
    for (int k = 0; k < 4; k++) *(uint4*)(As + tid * 40 + k * 8) = pk.v[k];
  }
  __syncthreads();

  f32x4 acc[4][2];
  #pragma unroll
  for (int rt = 0; rt < 4; rt++)
    #pragma unroll
    for (int ct = 0; ct < 2; ct++)
      acc[rt][ct] = (f32x4){0.f, 0.f, 0.f, 0.f};
  {
    const int kl = quad * 8;
    bf16x8 af[4];
    #pragma unroll
    for (int rt = 0; rt < 4; rt++)
      af[rt] = *(const bf16x8*)(As + (rt * 16 + l16) * 40 + kl);
    #pragma unroll
    for (int ct = 0; ct < 2; ct++) {
      bf16x8 bfv = *(const bf16x8*)(W1T + (c0w + ct * 16 + l16) * 32 + kl);
      #pragma unroll
      for (int rt = 0; rt < 4; rt++)
        acc[rt][ct] = __builtin_amdgcn_mfma_f32_16x16x32_bf16(af[rt], bfv, acc[rt][ct], 0, 0, 0);
    }
  }
  #pragma unroll
  for (int ct = 0; ct < 2; ct++) {
    int n = c0w + ct * 16 + l16;
    float b1v = b1[n];
    #pragma unroll
    for (int rt = 0; rt < 4; rt++)
      #pragma unroll
      for (int r = 0; r < 4; r++)
        ts[(rt * 16 + quad * 4 + r) * AS_STRIDE + n] = f2bf1(acc[rt][ct][r] + b1v);
  }
  __syncthreads();

  { // LN + SiLU in place (bf16)
    int row = tid >> 2, sub = tid & 3;
    float s = 0.f, sq = 0.f, vals[32];
    #pragma unroll
    for (int i = 0; i < 32; i++) {
      float v = bf2f(ts[row * AS_STRIDE + sub + i * 4]);
      vals[i] = v; s += v; sq += v * v;
    }
    s += __shfl_xor(s, 1); sq += __shfl_xor(sq, 1);
    s += __shfl_xor(s, 2); sq += __shfl_xor(sq, 2);
    float mean = s * (1.f / 128.f);
    float rstd = rsq_f(sq * (1.f / 128.f) - mean * mean + 1e-5f);
    #pragma unroll
    for (int i = 0; i < 32; i++) {
      int c = sub + i * 4;
      float a = (vals[i] - mean) * rstd * g[c] + be[c];
      ts[row * AS_STRIDE + c] = f2bf1(silu_f(a));
    }
  }
  __syncthreads();

  f32x4 acc2[4][2];
  #pragma unroll
  for (int rt = 0; rt < 4; rt++)
    #pragma unroll
    for (int ct = 0; ct < 2; ct++)
      acc2[rt][ct] = (f32x4){0.f, 0.f, 0.f, 0.f};
  #pragma unroll
  for (int kk = 0; kk < 4; kk++) {
    const int kl = kk * 32 + quad * 8;
    bf16x8 af[4];
    #pragma unroll
    for (int rt = 0; rt < 4; rt++)
      af[rt] = *(const bf16x8*)(ts + (rt * 16 + l16) * AS_STRIDE + kl);
    #pragma unroll
    for (int ct = 0; ct < 2; ct++) {
      bf16x8 bfv = *(const bf16x8*)(W2T + (size_t)(c0w + ct * 16 + l16) * 128 + kl);
      #pragma unroll
      for (int rt = 0; rt < 4; rt++)
        acc2[rt][ct] = __builtin_amdgcn_mfma_f32_16x16x32_bf16(af[rt], bfv, acc2[rt][ct], 0, 0, 0);
    }
  }
  __syncthreads();   // ts reads done; rewrite with h
  #pragma unroll
  for (int ct = 0; ct < 2; ct++) {
    int n = c0w + ct * 16 + l16;
    float b2v = b2[n];
    #pragma unroll
    for (int rt = 0; rt < 4; rt++)
      #pragma unroll
      for (int r = 0; r < 4; r++) {
        int m = rt * 16 + quad * 4 + r;
        int node = m0 + m;
        u16 hb = f2bf1(acc2[rt][ct][r] + b2v);
        ts[m * AS_STRIDE + n] = hb;
        if (node < Nn) hbf[(size_t)node * 128 + n] = hb;
      }
  }
  __syncthreads();

  { // fused hd = h@W1d + b1, then hs = h@W1s (layer 0)
    f32x4 ah[4][2];
    #pragma unroll
    for (int rt = 0; rt < 4; rt++)
      #pragma unroll
      for (int ct = 0; ct < 2; ct++)
        ah[rt][ct] = (f32x4){0.f, 0.f, 0.f, 0.f};
    #pragma unroll
    for (int kk = 0; kk < 4; kk++) {
      const int kl = kk * 32 + quad * 8;
      bf16x8 af[4];
      #pragma unroll
      for (int rt = 0; rt < 4; rt++)
        af[rt] = *(const bf16x8*)(ts + (rt * 16 + l16) * AS_STRIDE + kl);
      #pragma unroll
      for (int ct = 0; ct < 2; ct++) {
        bf16x8 bd = *(const bf16x8*)(eW1T0 + (size_t)(c0w + ct * 16 + l16) * 256 + kl);
        #pragma unroll
        for (int rt = 0; rt < 4; rt++)
          ah[rt][ct] = __builtin_amdgcn_mfma_f32_16x16x32_bf16(af[rt], bd, ah[rt][ct], 0, 0, 0);
      }
    }
    #pragma unroll
    for (int ct = 0; ct < 2; ct++) {
      int n = c0w + ct * 16 + l16;
      float b1v = eb10[n];
      #pragma unroll
      for (int rt = 0; rt < 4; rt++)
        #pragma unroll
        for (int r = 0; r < 4; r++) {
          int node = m0 + rt * 16 + quad * 4 + r;
          if (node < Nn) hd_all[(size_t)node * 128 + n] = f2bf1(ah[rt][ct][r] + b1v);
        }
    }
    #pragma unroll
    for (int rt = 0; rt < 4; rt++)
      #pragma unroll
      for (int ct = 0; ct < 2; ct++)
        ah[rt][ct] = (f32x4){0.f, 0.f, 0.f, 0.f};
    #pragma unroll
    for (int kk = 0; kk < 4; kk++) {
      const int kl = kk * 32 + quad * 8;
      bf16x8 af[4];
      #pragma unroll
      for (int rt = 0; rt < 4; rt++)
        af[rt] = *(const bf16x8*)(ts + (rt * 16 + l16) * AS_STRIDE + kl);
      #pragma unroll
      for (int ct = 0; ct < 2; ct++) {
        bf16x8 bs = *(const bf16x8*)(eW1T0 + (size_t)(c0w + ct * 16 + l16) * 256 + 128 + kl);
        #pragma unroll
        for (int rt = 0; rt < 4; rt++)
          ah[rt][ct] = __builtin_amdgcn_mfma_f32_16x16x32_bf16(af[rt], bs, ah[rt][ct], 0, 0, 0);
      }
    }
    #pragma unroll
    for (int ct = 0; ct < 2; ct++) {
      int n = c0w + ct * 16 + l16;
      #pragma unroll
      for (int rt = 0; rt < 4; rt++)
        #pragma unroll
        for (int r = 0; r < 4; r++) {
          int node = m0 + rt * 16 + quad * 4 + r;
          if (node < Nn) hs_all[(size_t)node * 128 + n] = f2bf1(ah[rt][ct][r]);
        }
    }
  }
}

// ---------------- edge MLP: top-pinned gather prefetch + MFMA ea-term --------
__global__ __launch_bounds__(256, 4)
void edge_mlp_kernel(const int* __restrict__ ssrc, const int* __restrict__ sdst,
                     const float* __restrict__ pos,
                     const u16* __restrict__ hd_all, const u16* __restrict__ hs_all,
                     const u16* __restrict__ w1cT,  // [128][32] bf16
                     const float* __restrict__ g, const float* __restrict__ be,
                     const u16* __restrict__ W2T,   // [128][128] bf16
                     const float* __restrict__ b2,
                     float* __restrict__ aggr) {
  __shared__ int s_dst[64];
  __shared__ __align__(16) u16 s_eaA[64 * 40];        // ea feats (K padded 32)
  __shared__ __align__(16) u16 s_t[64 * AS_STRIDE];   // t_ea -> u
  __shared__ __align__(16) u16 s_msg[128 * 68];       // col-major bf16 msg
  // ~40.2 KB -> pins residency at 4 blocks/CU (r4 lesson: more blocks thrash L2)

  const int tid = threadIdx.x;
  // XCD swizzle: consecutive-dst chunks stay on one XCD (hw: block -> XCD via %8)
  const int bid = blockIdx.x;
  const int e0 = ((bid & 7) * (gridDim.x >> 3) + (bid >> 3)) * 64;
  const int w = tid >> 6, lane = tid & 63, quad = lane >> 4, l16 = lane & 15;
  const int c0w = w * 32;
  const int rg = tid >> 4, cg = tid & 15;
  const int c0 = cg * 8;

  // ---- prefetch ALL phase-A gathers at kernel top; fence pins issue order ----
  int pdst[4], psrc[4];
  #pragma unroll
  for (int rr = 0; rr < 4; rr++) {
    pdst[rr] = sdst[e0 + rg * 4 + rr];
    psrc[rr] = ssrc[e0 + rg * 4 + rr];
  }
  uint4 hd4[4], hs4[4];
  #pragma unroll
  for (int rr = 0; rr < 4; rr++) {
    hd4[rr] = *(const uint4*)(hd_all + (size_t)pdst[rr] * 128 + c0);
    hs4[rr] = *(const uint4*)(hs_all + (size_t)psrc[rr] * 128 + c0);
  }
  asm volatile("" ::: "memory");  // compiler fence: loads cannot sink below

  if (tid < 64) {
    int src = ssrc[e0 + tid], dst = sdst[e0 + tid];
    s_dst[tid] = dst;
    float dx = pos[dst * 3 + 0] - pos[src * 3 + 0];
    float dy = pos[dst * 3 + 1] - pos[src * 3 + 1];
    float dz = pos[dst * 3 + 2] - pos[src * 3 + 2];
    float dist = sqrtf(dx * dx + dy * dy + dz * dz) + 1e-8f;
    float inv = __builtin_amdgcn_rcpf(dist);
    union { u16 us[40]; uint4 v[5]; } pk;
    #pragma unroll
    for (int k = 0; k < 40; k++) pk.us[k] = 0;
    pk.us[0] = f2bf1(dist);
    pk.us[1] = f2bf1(dx * inv); pk.us[2] = f2bf1(dy * inv); pk.us[3] = f2bf1(dz * inv);
    pk.us[4] = f2bf1(__builtin_amdgcn_rcpf(dist * dist + 1e-6f));
    #pragma unroll
    for (int k = 0; k < 5; k++) *(uint4*)(s_eaA + tid * 40 + k * 8) = pk.v[k];
  }
  __syncthreads();

  { // ea @ w1c on the MFMA pipe -> t_ea in s_t (bf16 row-major)
    f32x4 ae[4][2];
    #pragma unroll
    for (int rt = 0; rt < 4; rt++)
      #pragma unroll
      for (int ct = 0; ct < 2; ct++)
        ae[rt][ct] = (f32x4){0.f, 0.f, 0.f, 0.f};
    const int kl = quad * 8;
    bf16x8 afe[4];
    #pragma unroll
    for (int rt = 0; rt < 4; rt++)
      afe[rt] = *(const bf16x8*)(s_eaA + (rt * 16 + l16) * 40 + kl);
    #pragma unroll
    for (int ct = 0; ct < 2; ct++) {
      bf16x8 bw = *(const bf16x8*)(w1cT + (c0w + ct * 16 + l16) * 32 + kl);
      #pragma unroll
      for (int rt = 0; rt < 4; rt++)
        ae[rt][ct] = __builtin_amdgcn_mfma_f32_16x16x32_bf16(afe[rt], bw, ae[rt][ct], 0, 0, 0);
    }
    #pragma unroll
    for (int ct = 0; ct < 2; ct++) {
      int n = c0w + ct * 16 + l16;
      #pragma unroll
      for (int rt = 0; rt < 4; rt++)
        #pragma unroll
        for (int r = 0; r < 4; r++)
          s_t[(rt * 16 + quad * 4 + r) * AS_STRIDE + n] = f2bf1(ae[rt][ct][r]);
    }
  }
  __syncthreads();

  { // phase A: t = t_ea + hd[dst] + hs[src]; LN+SiLU -> u in s_t
    f32x2 g2[4], be2[4];
    {
      f32x4 ga = *(const f32x4*)(g + c0), gb = *(const f32x4*)(g + c0 + 4);
      f32x4 ba = *(const f32x4*)(be + c0), bb = *(const f32x4*)(be + c0 + 4);
      g2[0] = (f32x2){ga[0], ga[1]}; g2[1] = (f32x2){ga[2], ga[3]};
      g2[2] = (f32x2){gb[0], gb[1]}; g2[3] = (f32x2){gb[2], gb[3]};
      be2[0] = (f32x2){ba[0], ba[1]}; be2[1] = (f32x2){ba[2], ba[3]};
      be2[2] = (f32x2){bb[0], bb[1]}; be2[3] = (f32x2){bb[2], bb[3]};
    }
    #pragma unroll
    for (int rr = 0; rr < 4; rr++) {
      int m = rg * 4 + rr;
      uint4 te4 = *(const uint4*)(s_t + m * AS_STRIDE + c0);
      u32 hp[4] = {hd4[rr].x, hd4[rr].y, hd4[rr].z, hd4[rr].w};
      u32 sp[4] = {hs4[rr].x, hs4[rr].y, hs4[rr].z, hs4[rr].w};
      u32 tp[4] = {te4.x, te4.y, te4.z, te4.w};
      f32x2 t2[4], sm2 = (f32x2){0.f, 0.f}, sq2 = (f32x2){0.f, 0.f};
      #pragma unroll
      for (int p = 0; p < 4; p++) {
        t2[p] = unpk2(hp[p]) + unpk2(sp[p]) + unpk2(tp[p]);
        sm2 += t2[p];
        sq2 += t2[p] * t2[p];
      }
      float sm = sm2[0] + sm2[1], sq = sq2[0] + sq2[1];
      sm += __shfl_xor(sm, 1);  sq += __shfl_xor(sq, 1);
      sm += __shfl_xor(sm, 2);  sq += __shfl_xor(sq, 2);
      sm += __shfl_xor(sm, 4);  sq += __shfl_xor(sq, 4);
      sm += __shfl_xor(sm, 8);  sq += __shfl_xor(sq, 8);
      float mean = sm * (1.f / 128.f);
      float rstd = rsq_f(sq * (1.f / 128.f) - mean * mean + 1e-5f);
      f32x2 sc = (f32x2){rstd, rstd};
      f32x2 ofs = (f32x2){-mean * rstd, -mean * rstd};
      float o[8];
      #pragma unroll
      for (int p = 0; p < 4; p++) {
        f32x2 a = t2[p] * sc + ofs;
        a = a * g2[p] + be2[p];
        o[2 * p]     = silu_f(a[0]);
        o[2 * p + 1] = silu_f(a[1]);
      }
      uint4 st;
      st.x = cvt2bf(o[0], o[1]); st.y = cvt2bf(o[2], o[3]);
      st.z = cvt2bf(o[4], o[5]); st.w = cvt2bf(o[6], o[7]);
      *(uint4*)(s_t + m * AS_STRIDE + c0) = st;
    }
  }
  __syncthreads();

  f32x4 acc2[4][2];
  #pragma unroll
  for (int rt = 0; rt < 4; rt++)
    #pragma unroll
    for (int ct = 0; ct < 2; ct++)
      acc2[rt][ct] = (f32x4){0.f, 0.f, 0.f, 0.f};

  #pragma unroll
  for (int kk = 0; kk < 4; kk++) {               // K=128
    const int kl = kk * 32 + quad * 8;
    bf16x8 af[4];
    #pragma unroll
    for (int rt = 0; rt < 4; rt++)
      af[rt] = *(const bf16x8*)(s_t + (rt * 16 + l16) * AS_STRIDE + kl);
    #pragma unroll
    for (int ct = 0; ct < 2; ct++) {
      bf16x8 bfv = *(const bf16x8*)(W2T + (size_t)(c0w + ct * 16 + l16) * 128 + kl);
      #pragma unroll
      for (int rt = 0; rt < 4; rt++)
        acc2[rt][ct] = __builtin_amdgcn_mfma_f32_16x16x32_bf16(af[rt], bfv, acc2[rt][ct], 0, 0, 0);
    }
  }

  #pragma unroll
  for (int ct = 0; ct < 2; ct++) {
    int n = c0w + ct * 16 + l16;
    float b2v = b2[n];
    #pragma unroll
    for (int rt = 0; rt < 4; rt++) {
      int mb = rt * 16 + quad * 4;
      uint2 st;
      st.x = cvt2bf(acc2[rt][ct][0] + b2v, acc2[rt][ct][1] + b2v);
      st.y = cvt2bf(acc2[rt][ct][2] + b2v, acc2[rt][ct][3] + b2v);
      *(uint2*)(s_msg + n * 68 + mb) = st;
    }
  }
  __syncthreads();

  { // segmented column-sum over sorted dst runs (b64 reads, f32 accumulate)
    int c = tid & 127, q = tid >> 7;
    int r0 = q * 32;
    const u16* mp = s_msg + c * 68 + r0;
    float run = 0.f; int cur = s_dst[r0];
    #pragma unroll
    for (int i = 0; i < 8; i++) {
      uint2 pr = *(const uint2*)(mp + 4 * i);
      union { u32 u; float f; } va, vb, vc, vd;
      va.u = pr.x << 16; vb.u = pr.x & 0xffff0000u;
      vc.u = pr.y << 16; vd.u = pr.y & 0xffff0000u;
      int rb = r0 + 4 * i;
      int d0 = s_dst[rb], d1 = s_dst[rb + 1], d2 = s_dst[rb + 2], d3 = s_dst[rb + 3];
      if (d0 != cur) { atomicAdd(&aggr[(size_t)cur * 128 + c], run); run = 0.f; cur = d0; }
      run += va.f;
      if (d1 != cur) { atomicAdd(&aggr[(size_t)cur * 128 + c], run); run = 0.f; cur = d1; }
      run += vb.f;
      if (d2 != cur) { atomicAdd(&aggr[(size_t)cur * 128 + c], run); run = 0.f; cur = d2; }
      run += vc.f;
      if (d3 != cur) { atomicAdd(&aggr[(size_t)cur * 128 + c], run); run = 0.f; cur = d3; }
      run += vd.f;
    }
    atomicAdd(&aggr[(size_t)cur * 128 + c], run);
  }
}

// ------ node MLP + residual + outer LN + fused next hd/hs OR fused decoder ---
__global__ __launch_bounds__(256, 4)
void node_mlp_kernel(u16* __restrict__ hbf, float* __restrict__ aggr,
                     const u16* __restrict__ W1T, const float* __restrict__ b1,
                     const float* __restrict__ g, const float* __restrict__ be,
                     const u16* __restrict__ W2T, const float* __restrict__ b2,
                     const float* __restrict__ lng, const float* __restrict__ lnb,
                     const u16* __restrict__ W1Tn, const float* __restrict__ b1n,
                     u16* __restrict__ hd_all, u16* __restrict__ hs_all,
                     const float* __restrict__ x,
                     const u16* __restrict__ dW1T, const float* __restrict__ db1,
                     const u16* __restrict__ dW2T, const float* __restrict__ db2,
                     const u16* __restrict__ dW3T, const float* __restrict__ db3,
                     float* __restrict__ out,
                     int Nn) {
  __shared__ __align__(16) u16 As[128 * AS_STRIDE];  // 34,816 B
  u16* t_su = As;                    // [64][136]
  u16* u_su = As + 64 * AS_STRIDE;   // [64][136]

  const int tid = threadIdx.x;
  const int m0 = blockIdx.x * 64;
  const int w = tid >> 6, lane = tid & 63, quad = lane >> 4, l16 = lane & 15;
  const int c0w = w * 32;

  { // stage h (bf16 copy) + aggr (f32 -> bf16), then zero aggr for next layer
    int r = tid >> 4, c8 = (tid & 15) * 8;
    const float4 z4 = {0.f, 0.f, 0.f, 0.f};
    #pragma unroll
    for (int rp = 0; rp < 4; rp++) {
      int m = rp * 16 + r;
      int node = m0 + m; if (node >= Nn) node = Nn - 1;
      *(uint4*)(As + m * AS_STRIDE + c8) = *(const uint4*)(hbf + (size_t)node * 128 + c8);
      float* ap = aggr + (size_t)node * 128 + c8;
      float4 f0 = *(const float4*)ap;
      float4 f1 = *(const float4*)(ap + 4);
      uint4 pk;
      pk.x = cvt2bf(f0.x, f0.y); pk.y = cvt2bf(f0.z, f0.w);
      pk.z = cvt2bf(f1.x, f1.y); pk.w = cvt2bf(f1.z, f1.w);
      *(uint4*)(As + (64 + m) * AS_STRIDE + c8) = pk;
      *(float4*)ap = z4;
      *(float4*)(ap + 4) = z4;
    }
  }
  __syncthreads();

  f32x4 acc[4][2];
  #pragma unroll
  for (int rt = 0; rt < 4; rt++)
    #pragma unroll
    for (int ct = 0; ct < 2; ct++)
      acc[rt][ct] = (f32x4){0.f, 0.f, 0.f, 0.f};

  #pragma unroll
  for (int kk = 0; kk < 8; kk++) {
    const u16* Ab = As + (kk < 4 ? 0 : 64 * AS_STRIDE);
    const int kl = (kk & 3) * 32 + quad * 8;
    bf16x8 af[4];
    #pragma unroll
    for (int rt = 0; rt < 4; rt++)
      af[rt] = *(const bf16x8*)(Ab + (rt * 16 + l16) * AS_STRIDE + kl);
    const int kg = kk * 32 + quad * 8;
    #pragma unroll
    for (int ct = 0; ct < 2; ct++) {
      bf16x8 bfv = *(const bf16x8*)(W1T + (size_t)(c0w + ct * 16 + l16) * 256 + kg);
      #pragma unroll
      for (int rt = 0; rt < 4; rt++)
        acc[rt][ct] = __builtin_amdgcn_mfma_f32_16x16x32_bf16(af[rt], bfv, acc[rt][ct], 0, 0, 0);
    }
  }

  float b1v[2];
  #pragma unroll
  for (int ct = 0; ct < 2; ct++) b1v[ct] = b1[c0w + ct * 16 + l16];
  __syncthreads();

  #pragma unroll
  for (int rt = 0; rt < 4; rt++)
    #pragma unroll
    for (int ct = 0; ct < 2; ct++) {
      int n = c0w + ct * 16 + l16;
      #pragma unroll
      for (int r = 0; r < 4; r++)
        t_su[(rt * 16 + quad * 4 + r) * AS_STRIDE + n] = f2bf1(acc[rt][ct][r] + b1v[ct]);
    }
  __syncthreads();

  { // inner LN + SiLU: read t_su, write u_su
    int row = tid >> 2, sub = tid & 3;
    float s = 0.f, sq = 0.f, vals[32];
    #pragma unroll
    for (int i = 0; i < 32; i++) {
      float v = bf2f(t_su[row * AS_STRIDE + sub + i * 4]);
      vals[i] = v; s += v; sq += v * v;
    }
    s += __shfl_xor(s, 1); sq += __shfl_xor(sq, 1);
    s += __shfl_xor(s, 2); sq += __shfl_xor(sq, 2);
    float mean = s * (1.f / 128.f);
    float rstd = rsq_f(sq * (1.f / 128.f) - mean * mean + 1e-5f);
    #pragma unroll
    for (int i = 0; i < 32; i++) {
      int c = sub + i * 4;
      float a = (vals[i] - mean) * rstd * g[c] + be[c];
      u_su[row * AS_STRIDE + c] = f2bf1(silu_f(a));
    }
  }
  __syncthreads();

  f32x4 acc2[4][2];
  #pragma unroll
  for (int rt = 0; rt < 4; rt++)
    #pragma unroll
    for (int ct = 0; ct < 2; ct++)
      acc2[rt][ct] = (f32x4){0.f, 0.f, 0.f, 0.f};

  #pragma unroll
  for (int kk = 0; kk < 4; kk++) {
    const int kl = kk * 32 + quad * 8;
    bf16x8 af[4];
    #pragma unroll
    for (int rt = 0; rt < 4; rt++)
      af[rt] = *(const bf16x8*)(u_su + (rt * 16 + l16) * AS_STRIDE + kl);
    #pragma unroll
    for (int ct = 0; ct < 2; ct++) {
      bf16x8 bfv = *(const bf16x8*)(W2T + (size_t)(c0w + ct * 16 + l16) * 128 + kl);
      #pragma unroll
      for (int rt = 0; rt < 4; rt++)
        acc2[rt][ct] = __builtin_amdgcn_mfma_f32_16x16x32_bf16(af[rt], bfv, acc2[rt][ct], 0, 0, 0);
    }
  }
  __syncthreads();

  #pragma unroll
  for (int ct = 0; ct < 2; ct++) {
    int n = c0w + ct * 16 + l16;
    float b2v = b2[n];
    #pragma unroll
    for (int rt = 0; rt < 4; rt++)
      #pragma unroll
      for (int r = 0; r < 4; r++) {
        int m = rt * 16 + quad * 4 + r;
        int node = m0 + m; if (node >= Nn) node = Nn - 1;
        t_su[m * AS_STRIDE + n] =
            f2bf1(acc2[rt][ct][r] + b2v + bf2f(hbf[(size_t)node * 128 + n]));
      }
  }
  __syncthreads();

  { // outer LN -> hbf and back into t_su (A-layout h)
    int row = tid >> 2, sub = tid & 3;
    int node = m0 + row;
    float s = 0.f, sq = 0.f, vals[32];
    #pragma unroll
    for (int i = 0; i < 32; i++) {
      float v = bf2f(t_su[row * AS_STRIDE + sub + i * 4]);
      vals[i] = v; s += v; sq += v * v;
    }
    s += __shfl_xor(s, 1); sq += __shfl_xor(sq, 1);
    s += __shfl_xor(s, 2); sq += __shfl_xor(sq, 2);
    float mean = s * (1.f / 128.f);
    float rstd = rsq_f(sq * (1.f / 128.f) - mean * mean + 1e-5f);
    #pragma unroll
    for (int i = 0; i < 32; i++) {
      int c = sub + i * 4;
      float v = (vals[i] - mean) * rstd * lng[c] + lnb[c];
      u16 hb = f2bf1(v);
      t_su[row * AS_STRIDE + c] = hb;
      if (node < Nn) hbf[(size_t)node * 128 + c] = hb;
    }
  }

  if (W1Tn != nullptr) { // fused next-layer hd = h@W1d + b1, hs = h@W1s
    __syncthreads();
    f32x4 ah[4][2];
    #pragma unroll
    for (int rt = 0; rt < 4; rt++)
      #pragma unroll
      for (int ct = 0; ct < 2; ct++)
        ah[rt][ct] = (f32x4){0.f, 0.f, 0.f, 0.f};
    #pragma unroll
    for (int kk = 0; kk < 4; kk++) {
      const int kl = kk * 32 + quad * 8;
      bf16x8 af[4];
      #pragma unroll
      for (int rt = 0; rt < 4; rt++)
        af[rt] = *(const bf16x8*)(t_su + (rt * 16 + l16) * AS_STRIDE + kl);
      #pragma unroll
      for (int ct = 0; ct < 2; ct++) {
        bf16x8 bd = *(const bf16x8*)(W1Tn + (size_t)(c0w + ct * 16 + l16) * 256 + kl);
        #pragma unroll
        for (int rt = 0; rt < 4; rt++)
          ah[rt][ct] = __builtin_amdgcn_mfma_f32_16x16x32_bf16(af[rt], bd, ah[rt][ct], 0, 0, 0);
      }
    }
    #pragma unroll
    for (int ct = 0; ct < 2; ct++) {
      int n = c0w + ct * 16 + l16;
      float bv = b1n[n];
      #pragma unroll
      for (int rt = 0; rt < 4; rt++)
        #pragma unroll
        for (int r = 0; r < 4; r++) {
          int node = m0 + rt * 16 + quad * 4 + r;
          if (node < Nn) hd_all[(size_t)node * 128 + n] = f2bf1(ah[rt][ct][r] + bv);
        }
    }
    #pragma unroll
    for (int rt = 0; rt < 4; rt++)
      #pragma unroll
      for (int ct = 0; ct < 2; ct++)
        ah[rt][ct] = (f32x4){0.f, 0.f, 0.f, 0.f};
    #pragma unroll
    for (int kk = 0; kk < 4; kk++) {
      const int kl = kk * 32 + quad * 8;
      bf16x8 af[4];
      #pragma unroll
      for (int rt = 0; rt < 4; rt++)
        af[rt] = *(const bf16x8*)(t_su + (rt * 16 + l16) * AS_STRIDE + kl);
      #pragma unroll
      for (int ct = 0; ct < 2; ct++) {
        bf16x8 bs = *(const bf16x8*)(W1Tn + (size_t)(c0w + ct * 16 + l16) * 256 + 128 + kl);
        #pragma unroll
        for (int rt = 0; rt < 4; rt++)
          ah[rt][ct] = __builtin_amdgcn_mfma_f32_16x16x32_bf16(af[rt], bs, ah[rt][ct], 0, 0, 0);
      }
    }
    #pragma unroll
    for (int ct = 0; ct < 2; ct++) {
      int n = c0w + ct * 16 + l16;
      #pragma unroll
      for (int rt = 0; rt < 4; rt++)
        #pragma unroll
        for (int r = 0; r < 4; r++) {
          int node = m0 + rt * 16 + quad * 4 + r;
          if (node < Nn) hs_all[(size_t)node * 128 + n] = f2bf1(ah[rt][ct][r]);
        }
    }
  }

  if (dW1T != nullptr) { // fused decoder (layer 2): h in t_su (A-layout)
    __syncthreads();
    f32x4 da[4][2];
    #pragma unroll
    for (int rt = 0; rt < 4; rt++)
      #pragma unroll
      for (int ct = 0; ct < 2; ct++)
        da[rt][ct] = (f32x4){0.f, 0.f, 0.f, 0.f};
    #pragma unroll
    for (int kk = 0; kk < 4; kk++) {
      const int kl = kk * 32 + quad * 8;
      bf16x8 af[4];
      #pragma unroll
      for (int rt = 0; rt < 4; rt++)
        af[rt] = *(const bf16x8*)(t_su + (rt * 16 + l16) * AS_STRIDE + kl);
      #pragma unroll
      for (int ct = 0; ct < 2; ct++) {
        bf16x8 bfv = *(const bf16x8*)(dW1T + (size_t)(c0w + ct * 16 + l16) * 128 + kl);
        #pragma unroll
        for (int rt = 0; rt < 4; rt++)
          da[rt][ct] = __builtin_amdgcn_mfma_f32_16x16x32_bf16(af[rt], bfv, da[rt][ct], 0, 0, 0);
      }
    }
    __syncthreads();
    #pragma unroll
    for (int ct = 0; ct < 2; ct++) {
      int n = c0w + ct * 16 + l16;
      float bv = db1[n];
      #pragma unroll
      for (int rt = 0; rt < 4; rt++)
        #pragma unroll
        for (int r = 0; r < 4; r++)
          u_su[(rt * 16 + quad * 4 + r) * AS_STRIDE + n] = f2bf1(silu_f(da[rt][ct][r] + bv));
    }
    __syncthreads();
    { // dec L2: 64 cols, wave covers 16; u2 overwrites t_su region
      const int c0b = w * 16;
      f32x4 a2[4];
      #pragma unroll
      for (int rt = 0; rt < 4; rt++) a2[rt] = (f32x4){0.f, 0.f, 0.f, 0.f};
      #pragma unroll
      for (int kk = 0; kk < 4; kk++) {
        const int kl = kk * 32 + quad * 8;
        bf16x8 af[4];
        #pragma unroll
        for (int rt = 0; rt < 4; rt++)
          af[rt] = *(const bf16x8*)(u_su + (rt * 16 + l16) * AS_STRIDE + kl);
        bf16x8 bfv = *(const bf16x8*)(dW2T + (size_t)(c0b + l16) * 128 + kl);
        #pragma unroll
        for (int rt = 0; rt < 4; rt++)
          a2[rt] = __builtin_amdgcn_mfma_f32_16x16x32_bf16(af[rt], bfv, a2[rt], 0, 0, 0);
      }
      float bv = db2[c0b + l16];
      #pragma unroll
      for (int rt = 0; rt < 4; rt++)
        #pragma unroll
        for (int r = 0; r < 4; r++)
          t_su[(rt * 16 + quad * 4 + r) * 72 + c0b + l16] = f2bf1(silu_f(a2[rt][r] + bv));
    }
    __syncthreads();
    if (w == 0) { // dec L3: 6 cols (padded 16), K=64
      f32x4 a3[4];
      #pragma unroll
      for (int rt = 0; rt < 4; rt++) a3[rt] = (f32x4){0.f, 0.f, 0.f, 0.f};
      #pragma unroll
      for (int kk = 0; kk < 2; kk++) {
        const int kl = kk * 32 + quad * 8;
        bf16x8 af[4];
        #pragma unroll
        for (int rt = 0; rt < 4; rt++)
          af[rt] = *(const bf16x8*)(t_su + (rt * 16 + l16) * 72 + kl);
        bf16x8 bfv = *(const bf16x8*)(dW3T + l16 * 64 + kl);
        #pragma unroll
        for (int rt = 0; rt < 4; rt++)
          a3[rt] = __builtin_amdgcn_mfma_f32_16x16x32_bf16(af[rt], bfv, a3[rt], 0, 0, 0);
      }
      if (l16 < 6) {
        float bv = db3[l16];
        #pragma unroll
        for (int rt = 0; rt < 4; rt++)
          #pragma unroll
          for (int r = 0; r < 4; r++) {
            int node = m0 + rt * 16 + quad * 4 + r;
            if (node < Nn)
              out[(size_t)node * 6 + l16] = a3[rt][r] + bv + x[node * 7 + l16];
          }
      }
    }
  }
}

// ---------------- host launcher ----------------------------------------------
extern "C" void kernel_launch(void* const* d_in, const int* in_sizes, int n_in,
                              void* d_out, int out_size, void* d_ws, size_t ws_size,
                              hipStream_t stream) {
  const float* x      = (const float*)d_in[0];
  const float* pos    = (const float*)d_in[1];
  const int*   eidx   = (const int*)d_in[2];
  const float* enc_w1 = (const float*)d_in[3];
  const float* enc_b1 = (const float*)d_in[4];
  const float* enc_g  = (const float*)d_in[5];
  const float* enc_be = (const float*)d_in[6];
  const float* enc_w2 = (const float*)d_in[7];
  const float* enc_b2 = (const float*)d_in[8];
  const float* e_w1   = (const float*)d_in[9];
  const float* e_b1   = (const float*)d_in[10];
  const float* e_g    = (const float*)d_in[11];
  const float* e_be   = (const float*)d_in[12];
  const float* e_w2   = (const float*)d_in[13];
  const float* e_b2   = (const float*)d_in[14];
  const float* n_w1   = (const float*)d_in[15];
  const float* n_b1   = (const float*)d_in[16];
  const float* n_g    = (const float*)d_in[17];
  const float* n_be   = (const float*)d_in[18];
  const float* n_w2   = (const float*)d_in[19];
  const float* n_b2   = (const float*)d_in[20];
  const float* ln_g   = (const float*)d_in[21];
  const float* ln_b   = (const float*)d_in[22];
  const float* dec_w1 = (const float*)d_in[23];
  const float* dec_b1 = (const float*)d_in[24];
  const float* dec_w2 = (const float*)d_in[25];
  const float* dec_b2 = (const float*)d_in[26];
  const float* dec_w3 = (const float*)d_in[27];
  const float* dec_b3 = (const float*)d_in[28];

  const int N = in_sizes[0] / 7;          // 50000
  const int E = in_sizes[2] / 2;          // 1600000

  char* ws = (char*)d_ws;
  size_t off = 0;
  u16*   hbf    = (u16*)(ws + off);   off += (size_t)N * 128 * 2;
  u16*   hd_all = (u16*)(ws + off);   off += (size_t)N * 128 * 2;
  u16*   hs_all = (u16*)(ws + off);   off += (size_t)N * 128 * 2;
  float* aggr   = (float*)(ws + off); off += (size_t)N * 128 * 4;
  u16* eW1T = (u16*)(ws + off); off += 3 * 128 * 256 * 2;
  u16* eW2T = (u16*)(ws + off); off += 3 * 128 * 128 * 2;
  u16* nW1T = (u16*)(ws + off); off += 3 * 128 * 256 * 2;
  u16* nW2T = (u16*)(ws + off); off += 3 * 128 * 128 * 2;
  u16* encW1T = (u16*)(ws + off); off += 128 * 32 * 2;
  u16* encW2T = (u16*)(ws + off); off += 128 * 128 * 2;
  u16* decW1T = (u16*)(ws + off); off += 128 * 128 * 2;
  u16* decW2T = (u16*)(ws + off); off += 64 * 128 * 2;
  u16* decW3T = (u16*)(ws + off); off += 16 * 64 * 2;
  u16* eW1cT  = (u16*)(ws + off); off += 3 * 128 * 32 * 2;
  int* cnt    = (int*)(ws + off); off += (size_t)N * 4;
  int* cursor = (int*)(ws + off); off += (size_t)N * 4;
  int* ssrc   = (int*)(ws + off); off += (size_t)E * 4;
  int* sdst   = (int*)(ws + off); off += (size_t)E * 4;

  // sort edges by dst once (reused across all 3 layers)
  hipMemsetAsync(cnt, 0, (size_t)N * 4, stream);
  edge_hist<<<(E + 255) / 256, 256, 0, stream>>>(eidx + E, E, cnt);
  scan_kernel<<<1, 1024, 0, stream>>>(cnt, cursor, N);
  edge_scatter<<<(E + 255) / 256, 256, 0, stream>>>(eidx, eidx + E, E, cursor, ssrc, sdst);

  prep_weights<<<1152, 256, 0, stream>>>(e_w1, e_w2, n_w1, n_w2, eW1T, eW2T, nW1T, nW2T);
  prep_weights2<<<228, 256, 0, stream>>>(enc_w1, enc_w2, dec_w1, dec_w2, dec_w3, e_w1,
                                         encW1T, encW2T, decW1T, decW2T, decW3T, eW1cT);

  // zero aggr ONCE; node_mlp re-zeroes its rows for the next layer after reading
  hipMemsetAsync(aggr, 0, (size_t)N * 128 * 4, stream);

  const int nblk = (N + 63) / 64;
  encoder_mfma<<<nblk, 256, 0, stream>>>(x, encW1T, enc_b1, enc_g, enc_be, encW2T, enc_b2,
                                         eW1T, e_b1, hbf, hd_all, hs_all, N);

  for (int l = 0; l < 3; l++) {
    edge_mlp_kernel<<<E / 64, 256, 0, stream>>>(
        ssrc, sdst, pos, hd_all, hs_all,
        eW1cT + (size_t)l * 4096,
        e_g + l * 128, e_be + l * 128,
        eW2T + (size_t)l * 128 * 128, e_b2 + l * 128, aggr);
    const u16* W1Tn = (l < 2) ? (eW1T + (size_t)(l + 1) * 128 * 256) : (const u16*)nullptr;
    const bool last = (l == 2);
    node_mlp_kernel<<<nblk, 256, 0, stream>>>(
        hbf, aggr,
        nW1T + (size_t)l * 128 * 256, n_b1 + l * 128, n_g + l * 128, n_be + l * 128,
        nW2T + (size_t)l * 128 * 128, n_b2 + l * 128,
        ln_g + l * 128, ln_b + l * 128,
        W1Tn, e_b1 + ((l + 1) % 3) * 128, hd_all, hs_all,
        x,
        last ? decW1T : (const u16*)nullptr, dec_b1,
        last ? decW2T : (const u16*)nullptr, dec_b2,
        last ? decW3T : (const u16*)nullptr, dec_b3,
        (float*)d_out, N);
  }
}